// Round 1
// baseline (133.732 us; speedup 1.0000x reference)
//
#include <hip/hip_runtime.h>
#include <math.h>

// Problem constants (from reference)
constexpr int VOCAB = 100000;
constexpr int EMBED = 128;   // 32 float4 per row
constexpr int BATCH = 16384;
constexpr int NEG   = 10;

constexpr int ELEMS_PER_BLOCK = 8;                 // 4 waves x 2 half-waves
constexpr int NBLOCKS = BATCH / ELEMS_PER_BLOCK;   // 2048, exact

// log(sigmoid(x)) = min(x,0) - log1p(exp(-|x|))  (numerically stable)
__device__ __forceinline__ float log_sigmoid(float x) {
    return fminf(x, 0.0f) - log1pf(expf(-fabsf(x)));
}

// One 32-lane half-wave per batch element. Lane handles 4 consecutive floats
// of the 128-dim embedding (float4 -> 32 lanes * 16B = 512B coalesced row).
template<bool USE_WS>
__global__ __launch_bounds__(256) void w2v_main(
    const int*   __restrict__ input_word,
    const int*   __restrict__ context_word,
    const int*   __restrict__ neg_samples,
    const float* __restrict__ W_in,
    const float* __restrict__ W_ctx,
    float*       __restrict__ target)   // USE_WS: per-block partials; else scalar out (atomic)
{
    const int tid  = threadIdx.x;
    const int lane = tid & 63;
    const int half = lane >> 5;      // 0 or 1
    const int sub  = lane & 31;      // lane within half-group
    const int wave = tid >> 6;       // 0..3

    const int elem = blockIdx.x * ELEMS_PER_BLOCK + wave * 2 + half;

    const int iw = input_word[elem];
    const int cw = context_word[elem];

    const float4* rin  = (const float4*)(W_in  + (size_t)iw * EMBED);
    const float4* rctx = (const float4*)(W_ctx + (size_t)cw * EMBED);

    const float4 vin  = rin[sub];
    const float4 vctx = rctx[sub];

    float p[1 + NEG];
    p[0] = vin.x * vctx.x + vin.y * vctx.y + vin.z * vctx.z + vin.w * vctx.w;

    // Load the 10 negative-sample indices (broadcast within the half-group),
    // then issue all 10 row gathers before consuming — max loads in flight.
    int nidx[NEG];
#pragma unroll
    for (int k = 0; k < NEG; ++k) nidx[k] = neg_samples[elem * NEG + k];

    float4 vneg[NEG];
#pragma unroll
    for (int k = 0; k < NEG; ++k) {
        const float4* rn = (const float4*)(W_ctx + (size_t)nidx[k] * EMBED);
        vneg[k] = rn[sub];
    }
#pragma unroll
    for (int k = 0; k < NEG; ++k) {
        p[1 + k] = vin.x * vneg[k].x + vin.y * vneg[k].y +
                   vin.z * vneg[k].z + vin.w * vneg[k].w;
    }

    // Butterfly reduce across the 32-lane half-group. XOR masks 1..16 only
    // flip bits 0..4 so lanes never cross the half boundary on wave64.
#pragma unroll
    for (int m = 16; m >= 1; m >>= 1) {
#pragma unroll
        for (int k = 0; k < 1 + NEG; ++k)
            p[k] += __shfl_xor(p[k], m, 64);
    }

    __shared__ float acc[ELEMS_PER_BLOCK];
    if (sub == 0) {
        float s = log_sigmoid(p[0]);           // positive score
#pragma unroll
        for (int k = 0; k < NEG; ++k)
            s += log_sigmoid(-p[1 + k]);       // neg_score = -dot
        acc[wave * 2 + half] = s;
    }
    __syncthreads();

    if (tid == 0) {
        float t = 0.0f;
#pragma unroll
        for (int i = 0; i < ELEMS_PER_BLOCK; ++i) t += acc[i];
        t *= (-1.0f / (float)BATCH);           // loss = -mean(...)
        if (USE_WS) {
            target[blockIdx.x] = t;
        } else {
            atomicAdd(target, t);
        }
    }
}

__global__ __launch_bounds__(256) void w2v_reduce(
    const float* __restrict__ partials, float* __restrict__ out, int n)
{
    float s = 0.0f;
    for (int i = threadIdx.x; i < n; i += 256) s += partials[i];
#pragma unroll
    for (int m = 32; m >= 1; m >>= 1) s += __shfl_xor(s, m, 64);
    __shared__ float a[4];
    if ((threadIdx.x & 63) == 0) a[threadIdx.x >> 6] = s;
    __syncthreads();
    if (threadIdx.x == 0) out[0] = a[0] + a[1] + a[2] + a[3];
}

__global__ void w2v_zero(float* out) { out[0] = 0.0f; }

extern "C" void kernel_launch(void* const* d_in, const int* in_sizes, int n_in,
                              void* d_out, int out_size, void* d_ws, size_t ws_size,
                              hipStream_t stream) {
    const int*   input_word   = (const int*)d_in[0];
    const int*   context_word = (const int*)d_in[1];
    const int*   neg_samples  = (const int*)d_in[2];
    const float* W_in         = (const float*)d_in[3];
    const float* W_ctx        = (const float*)d_in[4];
    float*       out          = (float*)d_out;

    if (ws_size >= NBLOCKS * sizeof(float)) {
        float* partials = (float*)d_ws;
        hipLaunchKernelGGL((w2v_main<true>), dim3(NBLOCKS), dim3(256), 0, stream,
                           input_word, context_word, neg_samples, W_in, W_ctx, partials);
        hipLaunchKernelGGL(w2v_reduce, dim3(1), dim3(256), 0, stream,
                           partials, out, NBLOCKS);
    } else {
        hipLaunchKernelGGL(w2v_zero, dim3(1), dim3(1), 0, stream, out);
        hipLaunchKernelGGL((w2v_main<false>), dim3(NBLOCKS), dim3(256), 0, stream,
                           input_word, context_word, neg_samples, W_in, W_ctx, out);
    }
}